// Round 3
// baseline (17577.307 us; speedup 1.0000x reference)
//
#include <hip/hip_runtime.h>
#include <hip/hip_bf16.h>
#include <math.h>

#define B_  256
#define T_  1024
#define S_  8
#define H_  256
#define L_  32
#define RH_ 32
#define NC  16   // clusters (batch groups of 16)
#define CB  16   // blocks per cluster (16 H-rows each)
#define MB  16   // batch rows per cluster
#define NR  16   // H rows per block
#define TPB 256  // w0=layer0, w1=layer1 x-side, w2=layer1 h-side, w3=LN/dt
#define FH  (B_*H_)   // elements per parity plane (ull each)

typedef __attribute__((ext_vector_type(8))) short bf16x8;
typedef __attribute__((ext_vector_type(4))) float f32x4;
typedef unsigned long long ull;
typedef unsigned int uint;

__device__ __forceinline__ void split_bf16(float v, short& hi, short& lo) {
    unsigned ub = __float_as_uint(v);
    float hf = __uint_as_float(ub & 0xffff0000u);
    hi = (short)(ub >> 16);
    lo = (short)(__float_as_uint(v - hf) >> 16);
}
__device__ __forceinline__ float join_bf16(uint packed) {
    float h = __uint_as_float((packed & 0xffffu) << 16);
    float l = __uint_as_float((packed >> 16) << 16);
    return h + l;
}

__global__ void __launch_bounds__(TPB, 1)
liquid_cfc_tag(const float* __restrict__ xs,      // [B,T,S]
               const float* __restrict__ tstamp,  // [B,T]
               const float* __restrict__ ln_g, const float* __restrict__ ln_b,
               const float* __restrict__ bb_w0, const float* __restrict__ bb_b0,
               const float* __restrict__ gx_w0, const float* __restrict__ gx_b0,
               const float* __restrict__ gh_w0, const float* __restrict__ gb0,
               const float* __restrict__ lt0,
               const float* __restrict__ bb_w1, const float* __restrict__ bb_b1,
               const float* __restrict__ gx_w1, const float* __restrict__ gx_b1,
               const float* __restrict__ gh_w1, const float* __restrict__ gb1,
               const float* __restrict__ lt1,
               const float* __restrict__ lp_w, const float* __restrict__ lp_b,
               const float* __restrict__ r1_w, const float* __restrict__ r1_b,
               const float* __restrict__ r2_w, const float* __restrict__ r2_b,
               float* __restrict__ out,
               ull* h0t,      // [2][B][H] tagged: (tag<<32)|(hi|lo<<16)
               ull* h1t,      // [2][B][H]
               ull* latg)     // [B][L] tagged latents
{
    const int tid  = threadIdx.x, lane = tid & 63, wid = tid >> 6;
    const int blk  = blockIdx.x,  c = blk >> 4,    j  = blk & 15;
    const int b0   = c * MB,      r0 = j * NR;
    const int n    = lane & 15,   quad = lane >> 4;

    __shared__ float s_xn[2][16][8];          // layernormed x_t, parity-buffered
    __shared__ float s_dt[4][16];             // dt, quad-buffered (reader lags writer by up to 2)
    __shared__ float s_gx0[16][8], s_bb0x[16][8];
    __shared__ float s_bg0[16], s_bf0[16], s_sp0[16];
    __shared__ float s_bg1[16], s_bf1[16], s_sp1[16];
    __shared__ float s_pg[2][16][16], s_pf[2][16][16];   // wave1 -> wave2 partials, parity-buffered

    // ---- one-time LDS init ----
    if (tid < 16) {
        s_bg0[tid] = gx_b0[r0+tid] + gb0[r0+tid];
        s_bf0[tid] = bb_b0[r0+tid];
        s_sp0[tid] = log1pf(expf(lt0[r0+tid]));
        s_bg1[tid] = gx_b1[r0+tid] + gb1[r0+tid];
        s_bf1[tid] = bb_b1[r0+tid];
        s_sp1[tid] = log1pf(expf(lt1[r0+tid]));
    }
    if (tid < 128) {
        int r = tid >> 3, s = tid & 7;
        s_gx0[r][s]  = gx_w0[(r0+r)*S_ + s];
        s_bb0x[r][s] = bb_w0[(r0+r)*(S_+H_) + s];
    }

    // ---- one-time: weight slices -> bf16 hi/lo MFMA B-fragments in registers ----
    bf16x8 whi[2][8], wlo[2][8];
    if (wid < 3) {
        const float* base[2]; int st[2], of[2];
        if (wid == 0)      { base[0]=gh_w0; st[0]=H_;   of[0]=0;  base[1]=bb_w0; st[1]=S_+H_; of[1]=S_; }
        else if (wid == 1) { base[0]=gx_w1; st[0]=H_;   of[0]=0;  base[1]=bb_w1; st[1]=2*H_;  of[1]=0;  }
        else               { base[0]=gh_w1; st[0]=H_;   of[0]=0;  base[1]=bb_w1; st[1]=2*H_;  of[1]=H_; }
        int row = r0 + n;
        for (int mt = 0; mt < 2; ++mt) {
            const float* bp = base[mt] + (size_t)row * st[mt] + of[mt];
            for (int kb = 0; kb < 8; ++kb) {
                const float* sp = bp + kb*32 + quad*8;
                #pragma unroll
                for (int jj = 0; jj < 8; ++jj) {
                    short h_, l_;
                    split_bf16(sp[jj], h_, l_);
                    whi[mt][kb][jj] = h_; wlo[mt][kb][jj] = l_;
                }
            }
        }
    }
    float lngv[8], lnbv[8];
    if (wid == 3 && lane < 16) {
        #pragma unroll
        for (int s = 0; s < 8; ++s) { lngv[s] = ln_g[s]; lnbv[s] = ln_b[s]; }
    }
    float h0own[4] = {0.f,0.f,0.f,0.f};
    float h1own[4] = {0.f,0.f,0.f,0.f};
    float tsPrev = 0.f;
    __syncthreads();

    // ---- main loop: epoch t computes layer0(step t) and layer1(step t-1) ----
    for (int t = 0; t <= T_; ++t) {
        const int p = t & 1, q = 1 - p;
        const bool act = (wid == 0 || wid == 3) ? (t < T_) : (t >= 1);

        // wave3: layernorm x_t + dt  (no cross-block dependence)
        if (wid == 3 && act && lane < 16) {
            int m = lane;
            const float* xp = xs + ((size_t)(b0+m) * T_ + t) * S_;
            float v[8]; float mu = 0.f;
            #pragma unroll
            for (int s = 0; s < 8; ++s) { v[s] = xp[s]; mu += v[s]; }
            mu *= 0.125f;
            float var = 0.f;
            #pragma unroll
            for (int s = 0; s < 8; ++s) { float d = v[s] - mu; var += d * d; }
            var *= 0.125f;
            float rstd = rsqrtf(var + 1e-5f);
            #pragma unroll
            for (int s = 0; s < 8; ++s) s_xn[p][m][s] = (v[s] - mu) * rstd * lngv[s] + lnbv[s];
            float ts = tstamp[(size_t)(b0+m) * T_ + t];
            float dt = (t == 0) ? 1.0f : fmaxf(ts - tsPrev, 1e-6f);
            tsPrev = ts;
            s_dt[t & 3][m] = dt;
        }

        // waves 0-2: tag-poll fused with A-fragment load, then MFMA
        f32x4 accg = {0.f,0.f,0.f,0.f}, accf = {0.f,0.f,0.f,0.f};
        if (wid < 3 && act) {
            const ull* plane = (wid == 2) ? (h1t + (size_t)q * FH) : (h0t + (size_t)q * FH);
            const uint tgt   = (wid == 2) ? (uint)(t - 1) : (uint)t;
            const ull* asrc  = plane + (size_t)(b0 + n) * H_;

            ull araw[64];
            bool ok;
            do {
                #pragma unroll
                for (int u = 0; u < 64; ++u) {
                    int kb = u >> 3, jj = u & 7;
                    araw[u] = __hip_atomic_load(&asrc[kb*32 + quad*8 + jj],
                                                __ATOMIC_RELAXED, __HIP_MEMORY_SCOPE_AGENT);
                }
                bool mine = true;
                #pragma unroll
                for (int u = 0; u < 64; ++u) mine &= ((uint)(araw[u] >> 32) == tgt);
                ok = (__ballot(mine) == ~0ull);
                if (!ok) __builtin_amdgcn_s_sleep(1);
            } while (!ok);

            #pragma unroll
            for (int kb = 0; kb < 8; ++kb) {
                bf16x8 ahi, alo;
                #pragma unroll
                for (int jj = 0; jj < 8; ++jj) {
                    uint pk = (uint)araw[kb*8 + jj];
                    ahi[jj] = (short)(pk & 0xffffu);
                    alo[jj] = (short)(pk >> 16);
                }
                accg = __builtin_amdgcn_mfma_f32_16x16x32_bf16(ahi, whi[0][kb], accg, 0,0,0);
                accg = __builtin_amdgcn_mfma_f32_16x16x32_bf16(alo, whi[0][kb], accg, 0,0,0);
                accg = __builtin_amdgcn_mfma_f32_16x16x32_bf16(ahi, wlo[0][kb], accg, 0,0,0);
                accf = __builtin_amdgcn_mfma_f32_16x16x32_bf16(ahi, whi[1][kb], accf, 0,0,0);
                accf = __builtin_amdgcn_mfma_f32_16x16x32_bf16(alo, whi[1][kb], accf, 0,0,0);
                accf = __builtin_amdgcn_mfma_f32_16x16x32_bf16(ahi, wlo[1][kb], accf, 0,0,0);
            }
            if (wid == 1) {
                #pragma unroll
                for (int i = 0; i < 4; ++i) {
                    s_pg[p][quad*4+i][n] = accg[i];
                    s_pf[p][quad*4+i][n] = accf[i];
                }
            }
        }

        __syncthreads();   // xn/dt ready; wave1 partials ready; all waves' loads consumed

        // wave0 epilogue: layer-0 cell for step t, publish h0[t] tagged t+1 into plane p
        if (wid == 0 && act) {
            #pragma unroll
            for (int i = 0; i < 4; ++i) {
                int m = quad*4 + i;
                float aG = accg[i] + s_bg0[n];
                float aF = accf[i] + s_bf0[n];
                #pragma unroll
                for (int s = 0; s < 8; ++s) {
                    float xv = s_xn[p][m][s];
                    aG += s_gx0[n][s] * xv;
                    aF += s_bb0x[n][s] * xv;
                }
                float g   = 1.f / (1.f + expf(-aG));
                float f   = tanhf(aF);
                float dec = expf(-s_dt[t & 3][m] * (s_sp0[n] + fabsf(g)));
                h0own[i]  = dec * h0own[i] + (1.f - dec) * f;
                short hi_, lo_;
                split_bf16(h0own[i], hi_, lo_);
                ull v = ((ull)(uint)(t + 1) << 32) |
                        (ull)(((uint)(unsigned short)hi_) | (((uint)(unsigned short)lo_) << 16));
                __hip_atomic_store(&h0t[(size_t)p*FH + (size_t)(b0+m)*H_ + (r0+n)], v,
                                   __ATOMIC_RELAXED, __HIP_MEMORY_SCOPE_AGENT);
            }
        }
        // wave2 epilogue: layer-1 cell for step t-1, publish h1[t-1] tagged t into plane p
        if (wid == 2 && t >= 1) {
            #pragma unroll
            for (int i = 0; i < 4; ++i) {
                int m = quad*4 + i;
                float aG = accg[i] + s_pg[p][m][n] + s_bg1[n];
                float aF = accf[i] + s_pf[p][m][n] + s_bf1[n];
                float g   = 1.f / (1.f + expf(-aG));
                float f   = tanhf(aF);
                float dec = expf(-s_dt[(t-1) & 3][m] * (s_sp1[n] + fabsf(g)));
                h1own[i]  = dec * h1own[i] + (1.f - dec) * f;
                short hi_, lo_;
                split_bf16(h1own[i], hi_, lo_);
                ull v = ((ull)(uint)t << 32) |
                        (ull)(((uint)(unsigned short)hi_) | (((uint)(unsigned short)lo_) << 16));
                __hip_atomic_store(&h1t[(size_t)p*FH + (size_t)(b0+m)*H_ + (r0+n)], v,
                                   __ATOMIC_RELAXED, __HIP_MEMORY_SCOPE_AGENT);
            }
        }
    }

    // ---- latent head: h1[T-1] lives in plane 0 with tag T ----
    if (tid < 32) {
        int lb = tid >> 1;
        int l  = j*2 + (tid & 1);
        const ull* hsrc = h1t + (size_t)(b0+lb) * H_;   // plane 0
        float acc = lp_b[l];
        for (int k = 0; k < H_; ++k) {
            ull v;
            do {
                v = __hip_atomic_load(&hsrc[k], __ATOMIC_RELAXED, __HIP_MEMORY_SCOPE_AGENT);
                if ((uint)(v >> 32) != (uint)T_) __builtin_amdgcn_s_sleep(1); else break;
            } while (true);
            acc += join_bf16((uint)v) * lp_w[l*H_ + k];
        }
        float lat = tanhf(acc);
        out[(b0+lb)*L_ + l] = lat;
        ull lv = (1ull << 32) | (ull)__float_as_uint(lat);
        __hip_atomic_store(&latg[(b0+lb)*L_ + l], lv,
                           __ATOMIC_RELAXED, __HIP_MEMORY_SCOPE_AGENT);
    }

    // ---- risk head (block 0 of each cluster), gated by latent tags ----
    if (j == 0 && tid < 16) {
        float latv[L_];
        #pragma unroll
        for (int l = 0; l < L_; ++l) {
            ull v;
            do {
                v = __hip_atomic_load(&latg[(b0+tid)*L_ + l],
                                      __ATOMIC_RELAXED, __HIP_MEMORY_SCOPE_AGENT);
                if ((uint)(v >> 32) != 1u) __builtin_amdgcn_s_sleep(1); else break;
            } while (true);
            latv[l] = __uint_as_float((uint)v);
        }
        float acc2 = r2_b[0];
        for (int j2 = 0; j2 < RH_; ++j2) {
            float z = r1_b[j2];
            #pragma unroll
            for (int l = 0; l < L_; ++l) z += r1_w[j2*L_ + l] * latv[l];
            float hid = 0.5f * z * (1.f + erff(z * 0.70710678118654752f)); // exact GELU
            acc2 += r2_w[j2] * hid;
        }
        out[B_*L_ + b0 + tid] = 1.f / (1.f + expf(-acc2));
    }
}

extern "C" void kernel_launch(void* const* d_in, const int* in_sizes, int n_in,
                              void* d_out, int out_size, void* d_ws, size_t ws_size,
                              hipStream_t stream) {
    (void)in_sizes; (void)n_in; (void)out_size; (void)ws_size;
    const float* xs     = (const float*)d_in[0];
    const float* tstamp = (const float*)d_in[1];
    const float* ln_g   = (const float*)d_in[2];
    const float* ln_b   = (const float*)d_in[3];
    const float* bb_w0  = (const float*)d_in[4];
    const float* bb_b0  = (const float*)d_in[5];
    const float* gx_w0  = (const float*)d_in[6];
    const float* gx_b0  = (const float*)d_in[7];
    const float* gh_w0  = (const float*)d_in[8];
    const float* gb0    = (const float*)d_in[9];
    const float* lt0    = (const float*)d_in[10];
    const float* bb_w1  = (const float*)d_in[11];
    const float* bb_b1  = (const float*)d_in[12];
    const float* gx_w1  = (const float*)d_in[13];
    const float* gx_b1  = (const float*)d_in[14];
    const float* gh_w1  = (const float*)d_in[15];
    const float* gb1    = (const float*)d_in[16];
    const float* lt1    = (const float*)d_in[17];
    const float* lp_w   = (const float*)d_in[18];
    const float* lp_b   = (const float*)d_in[19];
    const float* r1_w   = (const float*)d_in[20];
    const float* r1_b   = (const float*)d_in[21];
    const float* r2_w   = (const float*)d_in[22];
    const float* r2_b   = (const float*)d_in[23];

    // ws carve: h0t [2*FH] ull | h1t [2*FH] ull | latg [B*L] ull
    ull* h0t  = (ull*)d_ws;
    ull* h1t  = h0t + 2 * FH;
    ull* latg = h1t + 2 * FH;
    size_t zero_bytes = (size_t)(4 * FH + B_ * L_) * sizeof(ull);

    // zero tags+values: epoch 0/1 read tag==0/value==0; ws poisoned 0xAA otherwise
    hipMemsetAsync(d_ws, 0, zero_bytes, stream);

    liquid_cfc_tag<<<dim3(NC * CB), dim3(TPB), 0, stream>>>(
        xs, tstamp, ln_g, ln_b,
        bb_w0, bb_b0, gx_w0, gx_b0, gh_w0, gb0, lt0,
        bb_w1, bb_b1, gx_w1, gx_b1, gh_w1, gb1, lt1,
        lp_w, lp_b, r1_w, r1_b, r2_w, r2_b,
        (float*)d_out, h0t, h1t, latg);
}

// Round 4
// 7833.337 us; speedup vs baseline: 2.2439x; 2.2439x over previous
//
#include <hip/hip_runtime.h>
#include <hip/hip_bf16.h>
#include <math.h>

#define B_  256
#define T_  1024
#define S_  8
#define H_  256
#define L_  32
#define RH_ 32
#define NC  16   // clusters (batch groups of 16)
#define CB  16   // blocks per cluster (16 H-rows each)
#define MB  16   // batch rows per cluster
#define NR  16   // H rows per block
#define TPB 256  // w0=layer0, w1=layer1 x-side, w2=layer1 h-side, w3=LN/dt
#define FH  (B_*H_)   // elements per parity plane (uint each)

typedef __attribute__((ext_vector_type(8))) short bf16x8;
typedef __attribute__((ext_vector_type(4))) float f32x4;
typedef unsigned long long ull;
typedef unsigned int uint;

__device__ __forceinline__ void split_bf16(float v, short& hi, short& lo) {
    unsigned ub = __float_as_uint(v);
    float hf = __uint_as_float(ub & 0xffff0000u);
    hi = (short)(ub >> 16);
    lo = (short)(__float_as_uint(v - hf) >> 16);
}
__device__ __forceinline__ float join_bf16(uint packed) {
    float h = __uint_as_float((packed & 0xffffu) << 16);
    float l = __uint_as_float((packed >> 16) << 16);
    return h + l;
}

__global__ void __launch_bounds__(TPB, 1)
liquid_cfc_flag(const float* __restrict__ xs,      // [B,T,S]
                const float* __restrict__ tstamp,  // [B,T]
                const float* __restrict__ ln_g, const float* __restrict__ ln_b,
                const float* __restrict__ bb_w0, const float* __restrict__ bb_b0,
                const float* __restrict__ gx_w0, const float* __restrict__ gx_b0,
                const float* __restrict__ gh_w0, const float* __restrict__ gb0,
                const float* __restrict__ lt0,
                const float* __restrict__ bb_w1, const float* __restrict__ bb_b1,
                const float* __restrict__ gx_w1, const float* __restrict__ gx_b1,
                const float* __restrict__ gh_w1, const float* __restrict__ gb1,
                const float* __restrict__ lt1,
                const float* __restrict__ lp_w, const float* __restrict__ lp_b,
                const float* __restrict__ r1_w, const float* __restrict__ r1_b,
                const float* __restrict__ r2_w, const float* __restrict__ r2_b,
                float* __restrict__ out,
                uint* flag0,    // [NC][16] packed in one 64B line per cluster
                uint* flag2,    // [NC][16]
                uint* h0pk,     // [2][B][H] packed hi|lo<<16 bf16
                uint* h1pk,     // [2][B][H]
                ull*  latg)     // [B][L] tagged latents
{
    const int tid  = threadIdx.x, lane = tid & 63, wid = tid >> 6;
    const int blk  = blockIdx.x,  c = blk >> 4,    j  = blk & 15;
    const int b0   = c * MB,      r0 = j * NR;
    const int n    = lane & 15,   quad = lane >> 4;

    __shared__ float s_xn[2][16][8];          // layernormed x_t, parity-buffered
    __shared__ float s_dt[4][16];             // dt, quad-buffered
    __shared__ float s_gx0[16][8], s_bb0x[16][8];
    __shared__ float s_bg0[16], s_bf0[16], s_sp0[16];
    __shared__ float s_bg1[16], s_bf1[16], s_sp1[16];
    __shared__ float s_pg[2][16][16], s_pf[2][16][16];   // w1 -> w2 partials, parity-buffered

    // ---- one-time LDS init ----
    if (tid < 16) {
        s_bg0[tid] = gx_b0[r0+tid] + gb0[r0+tid];
        s_bf0[tid] = bb_b0[r0+tid];
        s_sp0[tid] = log1pf(expf(lt0[r0+tid]));
        s_bg1[tid] = gx_b1[r0+tid] + gb1[r0+tid];
        s_bf1[tid] = bb_b1[r0+tid];
        s_sp1[tid] = log1pf(expf(lt1[r0+tid]));
    }
    if (tid < 128) {
        int r = tid >> 3, s = tid & 7;
        s_gx0[r][s]  = gx_w0[(r0+r)*S_ + s];
        s_bb0x[r][s] = bb_w0[(r0+r)*(S_+H_) + s];
    }

    // ---- one-time: weight slices -> bf16 hi/lo MFMA B-fragments in registers ----
    bf16x8 whi[2][8], wlo[2][8];
    if (wid < 3) {
        const float* base[2]; int st[2], of[2];
        if (wid == 0)      { base[0]=gh_w0; st[0]=H_;   of[0]=0;  base[1]=bb_w0; st[1]=S_+H_; of[1]=S_; }
        else if (wid == 1) { base[0]=gx_w1; st[0]=H_;   of[0]=0;  base[1]=bb_w1; st[1]=2*H_;  of[1]=0;  }
        else               { base[0]=gh_w1; st[0]=H_;   of[0]=0;  base[1]=bb_w1; st[1]=2*H_;  of[1]=H_; }
        int row = r0 + n;
        for (int mt = 0; mt < 2; ++mt) {
            const float* bp = base[mt] + (size_t)row * st[mt] + of[mt];
            for (int kb = 0; kb < 8; ++kb) {
                const float* sp = bp + kb*32 + quad*8;
                #pragma unroll
                for (int jj = 0; jj < 8; ++jj) {
                    short h_, l_;
                    split_bf16(sp[jj], h_, l_);
                    whi[mt][kb][jj] = h_; wlo[mt][kb][jj] = l_;
                }
            }
        }
    }
    float lngv[8], lnbv[8];
    if (wid == 3 && lane < 16) {
        #pragma unroll
        for (int s = 0; s < 8; ++s) { lngv[s] = ln_g[s]; lnbv[s] = ln_b[s]; }
    }
    float h0own[4] = {0.f,0.f,0.f,0.f};
    float h1own[4] = {0.f,0.f,0.f,0.f};
    float tsPrev = 0.f;
    __syncthreads();

    // ---- main loop: epoch t computes layer0(step t) and layer1(step t-1) ----
    for (int t = 0; t <= T_; ++t) {
        const int p  = t & 1;
        const int cp = (t + 1) & 1;   // == (t-1)&1, consumer plane

        // wave3: layernorm x_t + dt (intra-block only)
        if (wid == 3 && t < T_ && lane < 16) {
            int m = lane;
            const float* xp = xs + ((size_t)(b0+m) * T_ + t) * S_;
            float v[8]; float mu = 0.f;
            #pragma unroll
            for (int s = 0; s < 8; ++s) { v[s] = xp[s]; mu += v[s]; }
            mu *= 0.125f;
            float var = 0.f;
            #pragma unroll
            for (int s = 0; s < 8; ++s) { float d = v[s] - mu; var += d * d; }
            var *= 0.125f;
            float rstd = rsqrtf(var + 1e-5f);
            #pragma unroll
            for (int s = 0; s < 8; ++s) s_xn[p][m][s] = (v[s] - mu) * rstd * lngv[s] + lnbv[s];
            float ts = tstamp[(size_t)(b0+m) * T_ + t];
            float dt = (t == 0) ? 1.0f : fmaxf(ts - tsPrev, 1e-6f);
            tsPrev = ts;
            s_dt[t & 3][m] = dt;
        }

        // waves 0-2: flag wait (tiny, one cacheline) then coalesced A load + MFMA
        f32x4 accg = {0.f,0.f,0.f,0.f}, accf = {0.f,0.f,0.f,0.f};
        const bool act = (wid == 0) ? (t < T_) : (wid < 3 ? (t >= 1) : false);
        if (act) {
            const uint* fl = ((wid == 2) ? flag2 : flag0) + c * 16;
            uint tgt = (wid == 2) ? ((t >= 2) ? (uint)t : 0u) : (uint)t;
            if (tgt > 0) {
                bool ok;
                do {
                    uint fv = __hip_atomic_load(&fl[n], __ATOMIC_RELAXED, __HIP_MEMORY_SCOPE_AGENT);
                    ok = (__ballot(fv >= tgt) == ~0ull);
                    if (!ok) __builtin_amdgcn_s_sleep(1);
                } while (!ok);
            }
            const uint* plane = ((wid == 2) ? h1pk : h0pk) + (size_t)cp * FH + (size_t)(b0+n) * H_;
            const ull* ap = (const ull*)plane;
            ull araw[32];
            #pragma unroll
            for (int u = 0; u < 32; ++u) {
                int kb = u >> 2, uu = u & 3;
                araw[u] = __hip_atomic_load(&ap[kb*16 + quad*4 + uu],
                                            __ATOMIC_RELAXED, __HIP_MEMORY_SCOPE_AGENT);
            }
            #pragma unroll
            for (int kb = 0; kb < 8; ++kb) {
                bf16x8 ahi, alo;
                #pragma unroll
                for (int uu = 0; uu < 4; ++uu) {
                    ull d = araw[kb*4 + uu];
                    uint p0 = (uint)d, p1 = (uint)(d >> 32);
                    ahi[uu*2]   = (short)(p0 & 0xffffu); alo[uu*2]   = (short)(p0 >> 16);
                    ahi[uu*2+1] = (short)(p1 & 0xffffu); alo[uu*2+1] = (short)(p1 >> 16);
                }
                accg = __builtin_amdgcn_mfma_f32_16x16x32_bf16(ahi, whi[0][kb], accg, 0,0,0);
                accg = __builtin_amdgcn_mfma_f32_16x16x32_bf16(alo, whi[0][kb], accg, 0,0,0);
                accg = __builtin_amdgcn_mfma_f32_16x16x32_bf16(ahi, wlo[0][kb], accg, 0,0,0);
                accf = __builtin_amdgcn_mfma_f32_16x16x32_bf16(ahi, whi[1][kb], accf, 0,0,0);
                accf = __builtin_amdgcn_mfma_f32_16x16x32_bf16(alo, whi[1][kb], accf, 0,0,0);
                accf = __builtin_amdgcn_mfma_f32_16x16x32_bf16(ahi, wlo[1][kb], accf, 0,0,0);
            }
            if (wid == 1) {
                #pragma unroll
                for (int i = 0; i < 4; ++i) {
                    s_pg[p][quad*4+i][n] = accg[i];
                    s_pf[p][quad*4+i][n] = accf[i];
                }
            }
        }

        __syncthreads();   // single barrier per epoch: xn/dt + w1 partials published

        // wave0 epilogue: layer-0 cell step t -> publish h0[t] plane p, then flag0
        if (wid == 0 && t < T_) {
            #pragma unroll
            for (int i = 0; i < 4; ++i) {
                int m = quad*4 + i;
                float aG = accg[i] + s_bg0[n];
                float aF = accf[i] + s_bf0[n];
                #pragma unroll
                for (int s = 0; s < 8; ++s) {
                    float xv = s_xn[p][m][s];
                    aG += s_gx0[n][s] * xv;
                    aF += s_bb0x[n][s] * xv;
                }
                float g   = 1.f / (1.f + expf(-aG));
                float f   = tanhf(aF);
                float dec = expf(-s_dt[t & 3][m] * (s_sp0[n] + fabsf(g)));
                h0own[i]  = dec * h0own[i] + (1.f - dec) * f;
                short hi_, lo_;
                split_bf16(h0own[i], hi_, lo_);
                uint pk = ((uint)(unsigned short)hi_) | (((uint)(unsigned short)lo_) << 16);
                __hip_atomic_store(&h0pk[(size_t)p*FH + (size_t)(b0+m)*H_ + (r0+n)], pk,
                                   __ATOMIC_RELAXED, __HIP_MEMORY_SCOPE_AGENT);
            }
            __builtin_amdgcn_s_waitcnt(0);   // h0 stores acked at coherence point
            if (lane == 0)
                __hip_atomic_store(&flag0[c*16 + j], (uint)(t + 1),
                                   __ATOMIC_RELAXED, __HIP_MEMORY_SCOPE_AGENT);
        }
        // wave2 epilogue: layer-1 cell step t-1 -> publish h1[t-1] plane p, then flag2
        if (wid == 2 && t >= 1) {
            #pragma unroll
            for (int i = 0; i < 4; ++i) {
                int m = quad*4 + i;
                float aG = accg[i] + s_pg[p][m][n] + s_bg1[n];
                float aF = accf[i] + s_pf[p][m][n] + s_bf1[n];
                float g   = 1.f / (1.f + expf(-aG));
                float f   = tanhf(aF);
                float dec = expf(-s_dt[(t-1) & 3][m] * (s_sp1[n] + fabsf(g)));
                h1own[i]  = dec * h1own[i] + (1.f - dec) * f;
                short hi_, lo_;
                split_bf16(h1own[i], hi_, lo_);
                uint pk = ((uint)(unsigned short)hi_) | (((uint)(unsigned short)lo_) << 16);
                __hip_atomic_store(&h1pk[(size_t)p*FH + (size_t)(b0+m)*H_ + (r0+n)], pk,
                                   __ATOMIC_RELAXED, __HIP_MEMORY_SCOPE_AGENT);
            }
            __builtin_amdgcn_s_waitcnt(0);   // h1 stores acked
            if (lane == 0)
                __hip_atomic_store(&flag2[c*16 + j], (uint)(t + 1),
                                   __ATOMIC_RELAXED, __HIP_MEMORY_SCOPE_AGENT);
        }
    }

    // ---- heads: wave 0 only (other waves exit; no further barriers) ----
    if (wid == 0) {
        // wait all peer w2 finished epoch T_ (h1[T-1] in plane 0)
        {
            const uint* fl = flag2 + c * 16;
            bool ok;
            do {
                uint fv = __hip_atomic_load(&fl[n], __ATOMIC_RELAXED, __HIP_MEMORY_SCOPE_AGENT);
                ok = (__ballot(fv >= (uint)(T_ + 1)) == ~0ull);
                if (!ok) __builtin_amdgcn_s_sleep(1);
            } while (!ok);
        }
        if (lane < 32) {
            int lb = lane >> 1;
            int l  = j*2 + (lane & 1);
            const ull* hsrc = (const ull*)(h1pk + (size_t)(b0+lb) * H_);  // plane 0
            float acc = lp_b[l];
            #pragma unroll 8
            for (int u = 0; u < H_/2; ++u) {
                ull d = __hip_atomic_load(&hsrc[u], __ATOMIC_RELAXED, __HIP_MEMORY_SCOPE_AGENT);
                acc += join_bf16((uint)d)        * lp_w[l*H_ + 2*u];
                acc += join_bf16((uint)(d >> 32)) * lp_w[l*H_ + 2*u + 1];
            }
            float lat = tanhf(acc);
            out[(b0+lb)*L_ + l] = lat;
            ull lv = (1ull << 32) | (ull)__float_as_uint(lat);
            __hip_atomic_store(&latg[(b0+lb)*L_ + l], lv,
                               __ATOMIC_RELAXED, __HIP_MEMORY_SCOPE_AGENT);
        }
        // risk head (block 0 of each cluster)
        if (j == 0 && lane < 16) {
            float latv[L_];
            #pragma unroll
            for (int l = 0; l < L_; ++l) {
                ull v;
                do {
                    v = __hip_atomic_load(&latg[(b0+lane)*L_ + l],
                                          __ATOMIC_RELAXED, __HIP_MEMORY_SCOPE_AGENT);
                    if ((uint)(v >> 32) != 1u) __builtin_amdgcn_s_sleep(1); else break;
                } while (true);
                latv[l] = __uint_as_float((uint)v);
            }
            float acc2 = r2_b[0];
            for (int j2 = 0; j2 < RH_; ++j2) {
                float z = r1_b[j2];
                #pragma unroll
                for (int l = 0; l < L_; ++l) z += r1_w[j2*L_ + l] * latv[l];
                float hid = 0.5f * z * (1.f + erff(z * 0.70710678118654752f)); // exact GELU
                acc2 += r2_w[j2] * hid;
            }
            out[B_*L_ + b0 + lane] = 1.f / (1.f + expf(-acc2));
        }
    }
}

extern "C" void kernel_launch(void* const* d_in, const int* in_sizes, int n_in,
                              void* d_out, int out_size, void* d_ws, size_t ws_size,
                              hipStream_t stream) {
    (void)in_sizes; (void)n_in; (void)out_size; (void)ws_size;
    const float* xs     = (const float*)d_in[0];
    const float* tstamp = (const float*)d_in[1];
    const float* ln_g   = (const float*)d_in[2];
    const float* ln_b   = (const float*)d_in[3];
    const float* bb_w0  = (const float*)d_in[4];
    const float* bb_b0  = (const float*)d_in[5];
    const float* gx_w0  = (const float*)d_in[6];
    const float* gx_b0  = (const float*)d_in[7];
    const float* gh_w0  = (const float*)d_in[8];
    const float* gb0    = (const float*)d_in[9];
    const float* lt0    = (const float*)d_in[10];
    const float* bb_w1  = (const float*)d_in[11];
    const float* bb_b1  = (const float*)d_in[12];
    const float* gx_w1  = (const float*)d_in[13];
    const float* gx_b1  = (const float*)d_in[14];
    const float* gh_w1  = (const float*)d_in[15];
    const float* gb1    = (const float*)d_in[16];
    const float* lt1    = (const float*)d_in[17];
    const float* lp_w   = (const float*)d_in[18];
    const float* lp_b   = (const float*)d_in[19];
    const float* r1_w   = (const float*)d_in[20];
    const float* r1_b   = (const float*)d_in[21];
    const float* r2_w   = (const float*)d_in[22];
    const float* r2_b   = (const float*)d_in[23];

    // ws carve: flag0 1KB | flag2 1KB | h0pk 512KB | h1pk 512KB | latg 64KB
    uint8_t* w = (uint8_t*)d_ws;
    uint* flag0 = (uint*)w;
    uint* flag2 = (uint*)(w + 1024);
    uint* h0pk  = (uint*)(w + 2048);
    uint* h1pk  = h0pk + 2 * FH;
    ull*  latg  = (ull*)(h1pk + 2 * FH);
    size_t zero_bytes = 2048 + (size_t)4 * FH * sizeof(uint) + (size_t)B_ * L_ * sizeof(ull);

    hipMemsetAsync(d_ws, 0, zero_bytes, stream);

    liquid_cfc_flag<<<dim3(NC * CB), dim3(TPB), 0, stream>>>(
        xs, tstamp, ln_g, ln_b,
        bb_w0, bb_b0, gx_w0, gx_b0, gh_w0, gb0, lt0,
        bb_w1, bb_b1, gx_w1, gx_b1, gh_w1, gb1, lt1,
        lp_w, lp_b, r1_w, r1_b, r2_w, r2_b,
        (float*)d_out, flag0, flag2, h0pk, h1pk, latg);
}

// Round 5
// 5790.094 us; speedup vs baseline: 3.0358x; 1.3529x over previous
//
#include <hip/hip_runtime.h>
#include <hip/hip_bf16.h>
#include <math.h>

#define B_  256
#define T_  1024
#define S_  8
#define H_  256
#define L_  32
#define RH_ 32
#define NC  16   // clusters (batch groups of 16)
#define CB  16   // blocks per cluster (16 H-rows each)
#define MB  16   // batch rows per cluster
#define NR  16   // H rows per block
#define TPB 256  // w0=layer0, w1=layer1 x-side, w2=layer1 h-side, w3=LN/dt (one step ahead)
#define FH  (B_*H_)

typedef __attribute__((ext_vector_type(8))) short bf16x8;
typedef __attribute__((ext_vector_type(4))) float f32x4;
typedef __attribute__((ext_vector_type(4))) unsigned int uint4v;
typedef unsigned long long ull;
typedef unsigned int uint;

#define L2E 1.4426950408889634f

__device__ __forceinline__ void split_bf16(float v, short& hi, short& lo) {
    unsigned ub = __float_as_uint(v);
    float hf = __uint_as_float(ub & 0xffff0000u);
    hi = (short)(ub >> 16);
    lo = (short)(__float_as_uint(v - hf) >> 16);
}
__device__ __forceinline__ float join_bf16(uint packed) {
    float h = __uint_as_float((packed & 0xffffu) << 16);
    float l = __uint_as_float((packed >> 16) << 16);
    return h + l;
}
__device__ __forceinline__ float fsigmoid(float a) {
    return __builtin_amdgcn_rcpf(1.f + __builtin_amdgcn_exp2f(-a * L2E));
}
__device__ __forceinline__ float ftanh(float a) {
    float e = __builtin_amdgcn_exp2f(a * (2.f * L2E));   // inf-safe: rcp(inf)=0
    return 1.f - 2.f * __builtin_amdgcn_rcpf(e + 1.f);
}
__device__ __forceinline__ float fexpneg(float y) {     // e^-y, y>=0
    return __builtin_amdgcn_exp2f(-y * L2E);
}

// ---- coherent (coherence-point) memory ops: bypass L1/L2 via sc0 sc1 ----
__device__ __forceinline__ uint ld_flag(const uint* p) {
    uint r;
    asm volatile("global_load_dword %0, %1, off sc0 sc1\n\ts_waitcnt vmcnt(0)"
                 : "=v"(r) : "v"(p) : "memory");
    return r;
}
__device__ __forceinline__ void st_u32(uint* p, uint v) {
    asm volatile("global_store_dword %0, %1, off sc0 sc1" :: "v"(p), "v"(v) : "memory");
}
__device__ __forceinline__ void waitvm0() { asm volatile("s_waitcnt vmcnt(0)" ::: "memory"); }
template<int OFS>
__device__ __forceinline__ void ld16(uint4v& r, const uint* base) {
    asm volatile("global_load_dwordx4 %0, %1, off offset:%c2 sc0 sc1"
                 : "=v"(r) : "v"(base), "i"(OFS) : "memory");
}
__device__ __forceinline__ void ld16d(uint4v& r, const uint* p) {
    asm volatile("global_load_dwordx4 %0, %1, off sc0 sc1" : "=v"(r) : "v"(p) : "memory");
}
template<int N>
__device__ __forceinline__ void guard4(uint4v& a, uint4v& b, uint4v& c, uint4v& d) {
    asm volatile("s_waitcnt vmcnt(%c4)"
                 : "+v"(a), "+v"(b), "+v"(c), "+v"(d) : "i"(N) : "memory");
}

// fragment-order storage index within a row: col -> qc*64 + kb*8 + jj
// (qc=(col>>3)&3, kb=col>>5, jj=col&7) so lane (n,quad) reads [quad*64,quad*64+64)
__global__ void __launch_bounds__(TPB, 1)
liquid_cfc_v5(const float* __restrict__ xs, const float* __restrict__ tstamp,
              const float* __restrict__ ln_g, const float* __restrict__ ln_b,
              const float* __restrict__ bb_w0, const float* __restrict__ bb_b0,
              const float* __restrict__ gx_w0, const float* __restrict__ gx_b0,
              const float* __restrict__ gh_w0, const float* __restrict__ gb0,
              const float* __restrict__ lt0,
              const float* __restrict__ bb_w1, const float* __restrict__ bb_b1,
              const float* __restrict__ gx_w1, const float* __restrict__ gx_b1,
              const float* __restrict__ gh_w1, const float* __restrict__ gb1,
              const float* __restrict__ lt1,
              const float* __restrict__ lp_w, const float* __restrict__ lp_b,
              const float* __restrict__ r1_w, const float* __restrict__ r1_b,
              const float* __restrict__ r2_w, const float* __restrict__ r2_b,
              float* __restrict__ out,
              uint* flag0, uint* flag2,     // [NC][32] (own line per cluster)
              uint* h0pk, uint* h1pk,       // [2][B][H] packed hi|lo<<16, fragment order
              ull*  latg)                   // [B][L] tagged latents
{
    const int tid  = threadIdx.x, lane = tid & 63, wid = tid >> 6;
    const int blk  = blockIdx.x,  c = blk >> 4,    j  = blk & 15;
    const int b0   = c * MB,      r0 = j * NR;
    const int n    = lane & 15,   quad = lane >> 4;

    __shared__ float s_xn[4][16][8];          // LN'd x, quad-buffered (computed 1 epoch ahead)
    __shared__ float s_dt[4][16];
    __shared__ float s_gx0[16][8], s_bb0x[16][8];
    __shared__ float s_bg0[16], s_bf0[16], s_sp0[16];
    __shared__ float s_bg1[16], s_bf1[16], s_sp1[16];
    __shared__ float s_pg[2][16][16], s_pf[2][16][16];   // w1 -> w2 partials

    // ---- one-time LDS init ----
    if (tid < 16) {
        s_bg0[tid] = gx_b0[r0+tid] + gb0[r0+tid];
        s_bf0[tid] = bb_b0[r0+tid];
        s_sp0[tid] = log1pf(expf(lt0[r0+tid]));
        s_bg1[tid] = gx_b1[r0+tid] + gb1[r0+tid];
        s_bf1[tid] = bb_b1[r0+tid];
        s_sp1[tid] = log1pf(expf(lt1[r0+tid]));
    }
    if (tid < 128) {
        int r = tid >> 3, s = tid & 7;
        s_gx0[r][s]  = gx_w0[(r0+r)*S_ + s];
        s_bb0x[r][s] = bb_w0[(r0+r)*(S_+H_) + s];
    }

    // ---- one-time: weight slices -> bf16 hi/lo MFMA B-fragments ----
    bf16x8 whi[2][8], wlo[2][8];
    if (wid < 3) {
        const float* base[2]; int st[2], of[2];
        if (wid == 0)      { base[0]=gh_w0; st[0]=H_; of[0]=0;  base[1]=bb_w0; st[1]=S_+H_; of[1]=S_; }
        else if (wid == 1) { base[0]=gx_w1; st[0]=H_; of[0]=0;  base[1]=bb_w1; st[1]=2*H_;  of[1]=0;  }
        else               { base[0]=gh_w1; st[0]=H_; of[0]=0;  base[1]=bb_w1; st[1]=2*H_;  of[1]=H_; }
        int row = r0 + n;
        for (int mt = 0; mt < 2; ++mt) {
            const float* bp = base[mt] + (size_t)row * st[mt] + of[mt];
            for (int kb = 0; kb < 8; ++kb) {
                const float* sp = bp + kb*32 + quad*8;
                #pragma unroll
                for (int jj = 0; jj < 8; ++jj) {
                    short h_, l_;
                    split_bf16(sp[jj], h_, l_);
                    whi[mt][kb][jj] = h_; wlo[mt][kb][jj] = l_;
                }
            }
        }
    }
    float lngv[8], lnbv[8], tsPrev = 0.f;
    if (wid == 3 && lane < 16) {
        #pragma unroll
        for (int s = 0; s < 8; ++s) { lngv[s] = ln_g[s]; lnbv[s] = ln_b[s]; }
        // step 0 LN/dt into slot 0
        int m = lane;
        const float* xp = xs + (size_t)(b0+m) * T_ * S_;
        float v[8]; float mu = 0.f;
        #pragma unroll
        for (int s = 0; s < 8; ++s) { v[s] = xp[s]; mu += v[s]; }
        mu *= 0.125f;
        float var = 0.f;
        #pragma unroll
        for (int s = 0; s < 8; ++s) { float d = v[s] - mu; var += d * d; }
        var *= 0.125f;
        float rstd = rsqrtf(var + 1e-5f);
        #pragma unroll
        for (int s = 0; s < 8; ++s) s_xn[0][m][s] = (v[s] - mu) * rstd * lngv[s] + lnbv[s];
        s_dt[0][m] = 1.0f;
        tsPrev = tstamp[(size_t)(b0+m) * T_];
    }
    float h0own[4] = {0.f,0.f,0.f,0.f};
    float h1own[4] = {0.f,0.f,0.f,0.f};
    const uint sidx = (uint)((((j*2 + (n>>3)) & 3) << 6) | ((j>>1) << 3) | (n & 7));
    __syncthreads();

    // ---- main loop: epoch t = layer0(step t) + layer1(step t-1) ----
    for (int t = 0; t <= T_; ++t) {
        const int p = t & 1, cp = (t + 1) & 1;

        // wave3: LN/dt for step t+1 (one ahead, quad-buffered)
        if (wid == 3 && lane < 16 && (t + 1) < T_) {
            int m = lane, tn = t + 1;
            const float* xp = xs + ((size_t)(b0+m) * T_ + tn) * S_;
            float v[8]; float mu = 0.f;
            #pragma unroll
            for (int s = 0; s < 8; ++s) { v[s] = xp[s]; mu += v[s]; }
            mu *= 0.125f;
            float var = 0.f;
            #pragma unroll
            for (int s = 0; s < 8; ++s) { float d = v[s] - mu; var += d * d; }
            var *= 0.125f;
            float rstd = rsqrtf(var + 1e-5f);
            #pragma unroll
            for (int s = 0; s < 8; ++s) s_xn[tn & 3][m][s] = (v[s] - mu) * rstd * lngv[s] + lnbv[s];
            float ts = tstamp[(size_t)(b0+m) * T_ + tn];
            s_dt[tn & 3][m] = fmaxf(ts - tsPrev, 1e-6f);
            tsPrev = ts;
        }

        f32x4 accg = {0.f,0.f,0.f,0.f}, accf = {0.f,0.f,0.f,0.f};
        const bool act = (wid == 0) ? (t < T_) : ((wid == 1 || wid == 2) ? (t >= 1) : false);
        if (act) {
            // C-init: fold bias (+ x-side for w0) before the flag wait
            if (wid == 0) {
                #pragma unroll
                for (int i = 0; i < 4; ++i) {
                    int m = quad*4 + i;
                    float ag = s_bg0[n], af = s_bf0[n];
                    #pragma unroll
                    for (int s = 0; s < 8; ++s) {
                        float xv = s_xn[t & 3][m][s];
                        ag += s_gx0[n][s] * xv;
                        af += s_bb0x[n][s] * xv;
                    }
                    accg[i] = ag; accf[i] = af;
                }
            } else if (wid == 2) {
                #pragma unroll
                for (int i = 0; i < 4; ++i) { accg[i] = s_bg1[n]; accf[i] = s_bf1[n]; }
            }
            // flag wait: one 4B coherent load per retry
            uint tgt = (wid == 2) ? ((t >= 2) ? (uint)t : 0u) : (uint)t;
            if (tgt) {
                const uint* fp = ((wid == 2) ? flag2 : flag0) + c*32 + n;
                while (__ballot(ld_flag(fp) < tgt)) { }
            }
            // A-fragment: 16 contiguous dwordx4 coherent loads, staged waits
            const uint* ab = ((wid == 2) ? h1pk : h0pk) + (size_t)cp * FH
                             + (size_t)(b0+n) * H_ + quad*64;
            uint4v d0,d1,d2,d3,d4,d5,d6,d7,d8,d9,d10,d11,d12,d13,d14,d15;
            ld16<0>(d0,ab);   ld16<16>(d1,ab);  ld16<32>(d2,ab);  ld16<48>(d3,ab);
            ld16<64>(d4,ab);  ld16<80>(d5,ab);  ld16<96>(d6,ab);  ld16<112>(d7,ab);
            ld16<128>(d8,ab); ld16<144>(d9,ab); ld16<160>(d10,ab);ld16<176>(d11,ab);
            ld16<192>(d12,ab);ld16<208>(d13,ab);ld16<224>(d14,ab);ld16<240>(d15,ab);

            auto do_kb = [&](int kb, uint4v A, uint4v Bv) {
                union { uint u[4]; bf16x8 v; } hi_, lo_;
                hi_.u[0] = __builtin_amdgcn_perm(A.y,  A.x,  0x05040100u);
                hi_.u[1] = __builtin_amdgcn_perm(A.w,  A.z,  0x05040100u);
                hi_.u[2] = __builtin_amdgcn_perm(Bv.y, Bv.x, 0x05040100u);
                hi_.u[3] = __builtin_amdgcn_perm(Bv.w, Bv.z, 0x05040100u);
                lo_.u[0] = __builtin_amdgcn_perm(A.y,  A.x,  0x07060302u);
                lo_.u[1] = __builtin_amdgcn_perm(A.w,  A.z,  0x07060302u);
                lo_.u[2] = __builtin_amdgcn_perm(Bv.y, Bv.x, 0x07060302u);
                lo_.u[3] = __builtin_amdgcn_perm(Bv.w, Bv.z, 0x07060302u);
                accg = __builtin_amdgcn_mfma_f32_16x16x32_bf16(hi_.v, whi[0][kb], accg, 0,0,0);
                accg = __builtin_amdgcn_mfma_f32_16x16x32_bf16(lo_.v, whi[0][kb], accg, 0,0,0);
                accg = __builtin_amdgcn_mfma_f32_16x16x32_bf16(hi_.v, wlo[0][kb], accg, 0,0,0);
                accf = __builtin_amdgcn_mfma_f32_16x16x32_bf16(hi_.v, whi[1][kb], accf, 0,0,0);
                accf = __builtin_amdgcn_mfma_f32_16x16x32_bf16(lo_.v, whi[1][kb], accf, 0,0,0);
                accf = __builtin_amdgcn_mfma_f32_16x16x32_bf16(hi_.v, wlo[1][kb], accf, 0,0,0);
            };
            guard4<12>(d0,d1,d2,d3);   do_kb(0,d0,d1);   do_kb(1,d2,d3);
            guard4<8>(d4,d5,d6,d7);    do_kb(2,d4,d5);   do_kb(3,d6,d7);
            guard4<4>(d8,d9,d10,d11);  do_kb(4,d8,d9);   do_kb(5,d10,d11);
            guard4<0>(d12,d13,d14,d15);do_kb(6,d12,d13); do_kb(7,d14,d15);

            if (wid == 1) {
                #pragma unroll
                for (int i = 0; i < 4; ++i) {
                    s_pg[p][quad*4+i][n] = accg[i];
                    s_pf[p][quad*4+i][n] = accf[i];
                }
            }
        }

        __syncthreads();   // single barrier: LN(t+1), w1 partials, all loads consumed

        if (wid == 0 && t < T_) {
            #pragma unroll
            for (int i = 0; i < 4; ++i) {
                int m = quad*4 + i;
                float g   = fsigmoid(accg[i]);
                float f   = ftanh(accf[i]);
                float dec = fexpneg(s_dt[t & 3][m] * (s_sp0[n] + fabsf(g)));
                h0own[i]  = dec * h0own[i] + (1.f - dec) * f;
                short hi_, lo_;
                split_bf16(h0own[i], hi_, lo_);
                st_u32(h0pk + (size_t)p*FH + (size_t)(b0+m)*H_ + sidx,
                       ((uint)(unsigned short)hi_) | (((uint)(unsigned short)lo_) << 16));
            }
            waitvm0();
            if (lane == 0) st_u32(flag0 + c*32 + j, (uint)(t + 1));
        }
        if (wid == 2 && t >= 1) {
            #pragma unroll
            for (int i = 0; i < 4; ++i) {
                int m = quad*4 + i;
                float g   = fsigmoid(accg[i] + s_pg[p][m][n]);
                float f   = ftanh(accf[i] + s_pf[p][m][n]);
                float dec = fexpneg(s_dt[(t-1) & 3][m] * (s_sp1[n] + fabsf(g)));
                h1own[i]  = dec * h1own[i] + (1.f - dec) * f;
                short hi_, lo_;
                split_bf16(h1own[i], hi_, lo_);
                st_u32(h1pk + (size_t)p*FH + (size_t)(b0+m)*H_ + sidx,
                       ((uint)(unsigned short)hi_) | (((uint)(unsigned short)lo_) << 16));
            }
            waitvm0();
            if (lane == 0) st_u32(flag2 + c*32 + j, (uint)(t + 1));
        }
    }

    // ---- heads (wave 0 only; no further block barriers) ----
    if (wid == 0) {
        {   // all peers' w2 done epoch T_: h1[T-1] in plane 0
            const uint* fp = flag2 + c*32 + n;
            while (__ballot(ld_flag(fp) < (uint)(T_ + 1))) { }
        }
        if (lane < 32) {
            int lb = lane >> 1, l = j*2 + (lane & 1);
            const uint* hb = h1pk + (size_t)(b0+lb) * H_;   // plane 0, fragment order
            float acc = lp_b[l];
            for (int cb2 = 0; cb2 < 8; ++cb2) {
                uint4v e0,e1,e2,e3,e4,e5,e6,e7;
                ld16d(e0, hb + (cb2*8+0)*4); ld16d(e1, hb + (cb2*8+1)*4);
                ld16d(e2, hb + (cb2*8+2)*4); ld16d(e3, hb + (cb2*8+3)*4);
                ld16d(e4, hb + (cb2*8+4)*4); ld16d(e5, hb + (cb2*8+5)*4);
                ld16d(e6, hb + (cb2*8+6)*4); ld16d(e7, hb + (cb2*8+7)*4);
                guard4<4>(e0,e1,e2,e3);
                uint4v ee[8] = {e0,e1,e2,e3,e4,e5,e6,e7};
                guard4<0>(ee[4],ee[5],ee[6],ee[7]);
                #pragma unroll
                for (int i2 = 0; i2 < 8; ++i2) {
                    int s0 = (cb2*8 + i2) * 4;
                    #pragma unroll
                    for (int k2 = 0; k2 < 4; ++k2) {
                        int s = s0 + k2;
                        int col = ((s>>3)&7)*32 + (s>>6)*8 + (s&7);
                        acc += join_bf16(((uint*)&ee[i2])[k2]) * lp_w[l*H_ + col];
                    }
                }
            }
            float lat = tanhf(acc);
            out[(b0+lb)*L_ + l] = lat;
            __hip_atomic_store(&latg[(b0+lb)*L_ + l], (1ull << 32) | (ull)__float_as_uint(lat),
                               __ATOMIC_RELAXED, __HIP_MEMORY_SCOPE_AGENT);
        }
        if (j == 0 && lane < 16) {
            float latv[L_];
            #pragma unroll
            for (int l = 0; l < L_; ++l) {
                ull v;
                do {
                    v = __hip_atomic_load(&latg[(b0+lane)*L_ + l],
                                          __ATOMIC_RELAXED, __HIP_MEMORY_SCOPE_AGENT);
                } while ((uint)(v >> 32) != 1u);
                latv[l] = __uint_as_float((uint)v);
            }
            float acc2 = r2_b[0];
            for (int j2 = 0; j2 < RH_; ++j2) {
                float z = r1_b[j2];
                #pragma unroll
                for (int l = 0; l < L_; ++l) z += r1_w[j2*L_ + l] * latv[l];
                float hid = 0.5f * z * (1.f + erff(z * 0.70710678118654752f)); // exact GELU
                acc2 += r2_w[j2] * hid;
            }
            out[B_*L_ + b0 + lane] = 1.f / (1.f + expf(-acc2));
        }
    }
}

extern "C" void kernel_launch(void* const* d_in, const int* in_sizes, int n_in,
                              void* d_out, int out_size, void* d_ws, size_t ws_size,
                              hipStream_t stream) {
    (void)in_sizes; (void)n_in; (void)out_size; (void)ws_size;
    const float* xs     = (const float*)d_in[0];
    const float* tstamp = (const float*)d_in[1];
    const float* ln_g   = (const float*)d_in[2];
    const float* ln_b   = (const float*)d_in[3];
    const float* bb_w0  = (const float*)d_in[4];
    const float* bb_b0  = (const float*)d_in[5];
    const float* gx_w0  = (const float*)d_in[6];
    const float* gx_b0  = (const float*)d_in[7];
    const float* gh_w0  = (const float*)d_in[8];
    const float* gb0    = (const float*)d_in[9];
    const float* lt0    = (const float*)d_in[10];
    const float* bb_w1  = (const float*)d_in[11];
    const float* bb_b1  = (const float*)d_in[12];
    const float* gx_w1  = (const float*)d_in[13];
    const float* gx_b1  = (const float*)d_in[14];
    const float* gh_w1  = (const float*)d_in[15];
    const float* gb1    = (const float*)d_in[16];
    const float* lt1    = (const float*)d_in[17];
    const float* lp_w   = (const float*)d_in[18];
    const float* lp_b   = (const float*)d_in[19];
    const float* r1_w   = (const float*)d_in[20];
    const float* r1_b   = (const float*)d_in[21];
    const float* r2_w   = (const float*)d_in[22];
    const float* r2_b   = (const float*)d_in[23];

    // ws carve: flag0 2KB | flag2 2KB | h0pk 512KB | h1pk 512KB | latg 64KB
    uint8_t* w = (uint8_t*)d_ws;
    uint* flag0 = (uint*)w;
    uint* flag2 = (uint*)(w + 2048);
    uint* h0pk  = (uint*)(w + 4096);
    uint* h1pk  = h0pk + 2 * FH;
    ull*  latg  = (ull*)(h1pk + 2 * FH);
    size_t zero_bytes = 4096 + (size_t)4 * FH * sizeof(uint) + (size_t)B_ * L_ * sizeof(ull);

    hipMemsetAsync(d_ws, 0, zero_bytes, stream);

    liquid_cfc_v5<<<dim3(NC * CB), dim3(TPB), 0, stream>>>(
        xs, tstamp, ln_g, ln_b,
        bb_w0, bb_b0, gx_w0, gx_b0, gh_w0, gb0, lt0,
        bb_w1, bb_b1, gx_w1, gx_b1, gh_w1, gb1, lt1,
        lp_w, lp_b, r1_w, r1_b, r2_w, r2_b,
        (float*)d_out, flag0, flag2, h0pk, h1pk, latg);
}